// Round 3
// baseline (75.561 us; speedup 1.0000x reference)
//
#include <hip/hip_runtime.h>
#include <hip/hip_bf16.h>
#include <hip/hip_cooperative_groups.h>

namespace cg = cooperative_groups;

// Reference collapses: softmax over singleton axis==1 -> attention weights == 1,
// so ctx[b,h] = sum_l fmap[b,l,h], out[b,t,c] = dot(ctx[b,:], W_gen[c,:]) + b_gen[c]
// broadcast over all t. LSTM / embedding / text are dead code.
//
// Fused single cooperative kernel: phase 1 (fmap row-sums -> ctx in d_ws),
// grid.sync(), phase 2 (tiny GEMM + 32x broadcast store). Removes the ~10us
// kernel-boundary overhead seen in the two-kernel version.

constexpr int Hd = 512;   // hidden (K)
constexpr int Cd = 4096;  // classes (N)
constexpr int Bd = 64;    // batch (M)
constexpr int Td = 32;    // timesteps (broadcast)
constexpr int Ld = 256;   // FH*FW

constexpr int NBLK = 512; // 2 blocks/CU on 256 CUs — co-resident for coop launch

// all-DPP 16-lane rotate-add (row_ror:N); CTRL 0x121..: ror1, 0x122: ror2, ...
template<int CTRL>
__device__ __forceinline__ float ror_add(float v) {
    int r = __builtin_amdgcn_update_dpp(0, __float_as_int(v), CTRL, 0xF, 0xF, false);
    return v + __int_as_float(r);
}

__global__ __launch_bounds__(256, 2) void fused(const float* __restrict__ fmap,
                                                const float* __restrict__ Wgen,
                                                const float* __restrict__ bgen,
                                                float* __restrict__ out,
                                                float* __restrict__ ctx) {
    const int tid  = threadIdx.x;
    const int lane = tid & 63;
    const int w    = tid >> 6;      // wave id in block (0..3)
    const int bk   = blockIdx.x;

    // ---------- phase 1: ctx[row] = sum of 256 contiguous floats ----------
    // 32768 rows; 512 blocks * 4 waves = 2048 waves -> 16 rows/wave
    {
        const float4* in4 = reinterpret_cast<const float4*>(fmap);
        const int row0 = (bk * 4 + w) * 16;
        #pragma unroll 4
        for (int r = 0; r < 16; ++r) {
            const int row = row0 + r;
            const float4 v = in4[(size_t)row * 64 + lane];
            float s = v.x + v.y + v.z + v.w;
            #pragma unroll
            for (int m = 1; m < 64; m <<= 1) s += __shfl_xor(s, m, 64);
            if (lane == 0) ctx[row] = s;
        }
    }

    cg::this_grid().sync();

    // ---------- phase 2: out[b][t][c] = ctx[b,:]·W[c,:] + bias, bcast t ----------
    // 1024 tiles (64 c-groups x 16 b-groups of 4). Block bk does tiles bk, bk+512
    // (same c-slice both times; blocks sharing a c-slice are bk ≡ const mod 8
    //  -> same XCD -> W served from that XCD's L2 after first touch).
    __shared__ float part[4 * 64 * 4];   // [wave][c_local][b_local]
    const int cpart = lane >> 4;
    const int hp    = lane & 15;
    const float4* W4 = reinterpret_cast<const float4*>(Wgen);
    const float4* X4 = reinterpret_cast<const float4*>(ctx);

    for (int tile = bk; tile < 1024; tile += NBLK) {
        const int cblk = (tile & 63) * 64;
        const int b0   = (tile >> 6) * 4;

        // ctx registers: xr[bb][j] = ctx[b0+bb][w*128 + j*64 + hp*4 .. +3]
        float4 xr[4][2];
        #pragma unroll
        for (int bb = 0; bb < 4; ++bb)
            #pragma unroll
            for (int j = 0; j < 2; ++j)
                xr[bb][j] = X4[(size_t)(b0 + bb) * 128 + w * 32 + j * 16 + hp];

        #pragma unroll 4
        for (int q = 0; q < 16; ++q) {
            const int c = cblk + q * 4 + cpart;
            const size_t base = (size_t)c * 128 + w * 32 + hp;
            const float4 w0 = W4[base];        // h = w*128 + hp*4
            const float4 w1 = W4[base + 16];   // h = w*128 + 64 + hp*4
            float acc[4];
            #pragma unroll
            for (int bb = 0; bb < 4; ++bb) {
                float a = w0.x * xr[bb][0].x + w0.y * xr[bb][0].y
                        + w0.z * xr[bb][0].z + w0.w * xr[bb][0].w
                        + w1.x * xr[bb][1].x + w1.y * xr[bb][1].y
                        + w1.z * xr[bb][1].z + w1.w * xr[bb][1].w;
                a = ror_add<0x128>(a);  // +ror8
                a = ror_add<0x124>(a);  // +ror4
                a = ror_add<0x122>(a);  // +ror2
                a = ror_add<0x121>(a);  // +ror1 -> full 16-lane sum everywhere
                acc[bb] = a;
            }
            if (hp == 0) {
                reinterpret_cast<float4*>(part)[w * 64 + (q * 4 + cpart)] =
                    make_float4(acc[0], acc[1], acc[2], acc[3]);
            }
        }
        __syncthreads();

        {
            const int cl = lane;     // c within slice
            const int bl = w;        // b within group
            float v = part[(0 * 64 + cl) * 4 + bl] + part[(1 * 64 + cl) * 4 + bl]
                    + part[(2 * 64 + cl) * 4 + bl] + part[(3 * 64 + cl) * 4 + bl]
                    + bgen[cblk + cl];
            float* o = out + (size_t)(b0 + bl) * Td * Cd + cblk + cl;
            #pragma unroll
            for (int t = 0; t < Td; ++t) o[(size_t)t * Cd] = v;  // 256B/wave
        }
        __syncthreads();  // part reused by next tile iteration
    }
}

extern "C" void kernel_launch(void* const* d_in, const int* in_sizes, int n_in,
                              void* d_out, int out_size, void* d_ws, size_t ws_size,
                              hipStream_t stream) {
    const float* fmap = (const float*)d_in[0];   // [64,512,8,32]
    const float* Wgen = (const float*)d_in[9];   // [4096,512]
    const float* bgen = (const float*)d_in[10];  // [4096]
    float* out = (float*)d_out;                  // [64,32,4096]
    float* ctx = (float*)d_ws;                   // [64,512] scratch

    void* args[] = {(void*)&fmap, (void*)&Wgen, (void*)&bgen, (void*)&out, (void*)&ctx};
    hipLaunchCooperativeKernel((const void*)fused, dim3(NBLK), dim3(256),
                               args, 0, stream);
}

// Round 4
// 25.705 us; speedup vs baseline: 2.9396x; 2.9396x over previous
//
#include <hip/hip_runtime.h>
#include <hip/hip_bf16.h>

// Reference collapses: softmax over singleton axis==1 -> attention weights == 1,
// so ctx[b,h] = sum_l fmap[b,l,h], out[b,t,c] = dot(ctx[b,:], W_gen[c,:]) + b_gen[c]
// broadcast over all t. LSTM / embedding / text are dead code.
//
// R3 post-mortem: cooperative fusion was latency-bound (occ 20%, VALU 8.6%,
// HBM 5%) — grid.sync cost + 16x parallelism loss in phase 1. Reverted to two
// kernels; this round doubles K2 parallelism, deepens its load pipeline, and
// vectorizes the broadcast stores.

constexpr int Hd = 512;   // hidden (K)
constexpr int Cd = 4096;  // classes (N)
constexpr int Bd = 64;    // batch (M)
constexpr int Td = 32;    // timesteps (broadcast)
constexpr int Ld = 256;   // FH*FW
constexpr int CG = 32;    // c per block in K2

// ---------------- K1: ctx[b*Hd+h] = sum of 256 contiguous floats ----------------
// one wave per row, 32768 independent waves — BW-bound by construction.
__global__ __launch_bounds__(256) void reduce_rows(const float* __restrict__ in,
                                                   float* __restrict__ ctx) {
    const int gtid = blockIdx.x * 256 + threadIdx.x;
    const int row  = gtid >> 6;
    const int lane = threadIdx.x & 63;
    const float4 v = reinterpret_cast<const float4*>(in + (size_t)row * Ld)[lane];
    float s = v.x + v.y + v.z + v.w;
    #pragma unroll
    for (int m = 1; m < 64; m <<= 1) s += __shfl_xor(s, m, 64);
    if (lane == 0) ctx[row] = s;
}

// all-DPP 16-lane rotate-add (row_ror:N); 0x121:ror1 0x122:ror2 0x124:ror4 0x128:ror8
template<int CTRL>
__device__ __forceinline__ float ror_add(float v) {
    int r = __builtin_amdgcn_update_dpp(0, __float_as_int(v), CTRL, 0xF, 0xF, false);
    return v + __int_as_float(r);
}

// ---------------- K2: out[b][t][c] = ctx[b,:]·W[c,:] + bias, bcast over t -------
// grid (Cd/CG=128, Bd/4=16) = 2048 blocks, 256 thr (4 waves).
// wave w owns K-slice h in [w*128, w*128+128); lane = cpart*16 + hp.
// Same-c-slice blocks differ only in blockIdx.y (linear-id stride 128 ≡ 0 mod 8)
// -> same XCD -> W slice (64KB) L2-resident across its 16 b-replicas.
__global__ __launch_bounds__(256) void gemm_bcast(const float* __restrict__ ctx,
                                                  const float* __restrict__ Wgen,
                                                  const float* __restrict__ bgen,
                                                  float* __restrict__ out) {
    __shared__ float part[4 * CG * 4];  // [wave][c_local][b_local]
    const int tid   = threadIdx.x;
    const int w     = tid >> 6;
    const int lane  = tid & 63;
    const int cpart = lane >> 4;
    const int hp    = lane & 15;
    const int cblk  = blockIdx.x * CG;
    const int b0    = blockIdx.y * 4;

    const float4* W4 = reinterpret_cast<const float4*>(Wgen);
    const float4* X4 = reinterpret_cast<const float4*>(ctx);

    // ctx registers: xr[bb][j] = ctx[b0+bb][w*128 + j*64 + hp*4 .. +3]
    float4 xr[4][2];
    #pragma unroll
    for (int bb = 0; bb < 4; ++bb)
        #pragma unroll
        for (int j = 0; j < 2; ++j)
            xr[bb][j] = X4[(size_t)(b0 + bb) * 128 + w * 32 + j * 16 + hp];

    #pragma unroll 4
    for (int q = 0; q < CG / 4; ++q) {
        const int c = cblk + q * 4 + cpart;
        const size_t base = (size_t)c * 128 + w * 32 + hp;
        const float4 w0 = W4[base];        // h = w*128 + hp*4
        const float4 w1 = W4[base + 16];   // h = w*128 + 64 + hp*4
        float acc[4];
        #pragma unroll
        for (int bb = 0; bb < 4; ++bb) {
            float a = w0.x * xr[bb][0].x + w0.y * xr[bb][0].y
                    + w0.z * xr[bb][0].z + w0.w * xr[bb][0].w
                    + w1.x * xr[bb][1].x + w1.y * xr[bb][1].y
                    + w1.z * xr[bb][1].z + w1.w * xr[bb][1].w;
            a = ror_add<0x128>(a);
            a = ror_add<0x124>(a);
            a = ror_add<0x122>(a);
            a = ror_add<0x121>(a);      // full 16-lane sum in every lane
            acc[bb] = a;
        }
        if (hp == 0) {
            reinterpret_cast<float4*>(part)[w * CG + (q * 4 + cpart)] =
                make_float4(acc[0], acc[1], acc[2], acc[3]);
        }
    }
    __syncthreads();

    // combine 4 wave-partials + bias, then float4 broadcast stores.
    // tid -> (cq 0..7, bl 0..3, tt 0..7); thread stores c-quad cq for b=b0+bl
    // at t = tt, tt+8, tt+16, tt+24  (1KB per wave per store instr).
    {
        const int cq = tid & 7;
        const int bl = (tid >> 3) & 3;
        const int tt = tid >> 5;
        float v[4];
        #pragma unroll
        for (int j = 0; j < 4; ++j) {
            const int cl = cq * 4 + j;
            v[j] = part[(0 * CG + cl) * 4 + bl] + part[(1 * CG + cl) * 4 + bl]
                 + part[(2 * CG + cl) * 4 + bl] + part[(3 * CG + cl) * 4 + bl]
                 + bgen[cblk + cl];
        }
        const float4 vv = make_float4(v[0], v[1], v[2], v[3]);
        float* o = out + (size_t)(b0 + bl) * Td * Cd + cblk + cq * 4;
        #pragma unroll
        for (int k = 0; k < 4; ++k) {
            const int t = tt + k * 8;
            *reinterpret_cast<float4*>(o + (size_t)t * Cd) = vv;
        }
    }
}

extern "C" void kernel_launch(void* const* d_in, const int* in_sizes, int n_in,
                              void* d_out, int out_size, void* d_ws, size_t ws_size,
                              hipStream_t stream) {
    const float* fmap = (const float*)d_in[0];   // [64,512,8,32]
    const float* Wgen = (const float*)d_in[9];   // [4096,512]
    const float* bgen = (const float*)d_in[10];  // [4096]
    float* out = (float*)d_out;                  // [64,32,4096]
    float* ctx = (float*)d_ws;                   // [64,512] scratch

    reduce_rows<<<dim3((Bd * Hd) / 4), dim3(256), 0, stream>>>(fmap, ctx);
    gemm_bcast<<<dim3(Cd / CG, Bd / 4), dim3(256), 0, stream>>>(ctx, Wgen, bgen, out);
}

// Round 5
// 24.498 us; speedup vs baseline: 3.0844x; 1.0493x over previous
//
#include <hip/hip_runtime.h>
#include <hip/hip_bf16.h>

// Reference collapses: softmax over singleton axis==1 -> attention weights == 1,
// so ctx[b,h] = sum_l fmap[b,l,h], out[b,t,c] = dot(ctx[b,:], W_gen[c,:]) + b_gen[c]
// broadcast over all t. LSTM / embedding / text are dead code.
//
// R4 post-mortem: K2 restructure moved only 1.5us -> K1 is the residual cost.
// K1 was 8192 tiny blocks (4KB reads each, 1 load/thread, 6-deep ds_bpermute
// chain) = dispatch-rate + reduce-latency bound. Now: 1024 blocks, 8 rows/wave
// (8 loads in flight), reduce = 2 shfl_xor + 4 DPP row_ror adds.

constexpr int Hd = 512;   // hidden (K)
constexpr int Cd = 4096;  // classes (N)
constexpr int Bd = 64;    // batch (M)
constexpr int Td = 32;    // timesteps (broadcast)
constexpr int Ld = 256;   // FH*FW
constexpr int CG = 32;    // c per block in K2

// all-DPP 16-lane rotate-add; 0x121:ror1 0x122:ror2 0x124:ror4 0x128:ror8
template<int CTRL>
__device__ __forceinline__ float ror_add(float v) {
    int r = __builtin_amdgcn_update_dpp(0, __float_as_int(v), CTRL, 0xF, 0xF, false);
    return v + __int_as_float(r);
}

// ---------------- K1: ctx[row] = sum of 256 contiguous floats ----------------
// grid 1024 x 256thr; wave = 8 rows, loads all issued up front.
__global__ __launch_bounds__(256) void reduce_rows(const float* __restrict__ in,
                                                   float* __restrict__ ctx) {
    const int lane = threadIdx.x & 63;
    const int gw   = blockIdx.x * 4 + (threadIdx.x >> 6);  // global wave 0..4095
    const int row0 = gw * 8;
    const float4* in4 = reinterpret_cast<const float4*>(in);

    float4 v[8];
    #pragma unroll
    for (int r = 0; r < 8; ++r)
        v[r] = in4[(size_t)(row0 + r) * 64 + lane];   // 8 independent loads

    float s[8];
    #pragma unroll
    for (int r = 0; r < 8; ++r) {
        float a = v[r].x + v[r].y + v[r].z + v[r].w;
        a += __shfl_xor(a, 16, 64);
        a += __shfl_xor(a, 32, 64);
        a = ror_add<0x121>(a);
        a = ror_add<0x122>(a);
        a = ror_add<0x124>(a);
        a = ror_add<0x128>(a);   // full 64-lane sum in every lane
        s[r] = a;
    }
    if (lane < 8) {
        // lane r stores row r's sum: all s[r] identical across lanes
        float val = s[0];
        #pragma unroll
        for (int r = 1; r < 8; ++r) val = (lane == r) ? s[r] : val;
        ctx[row0 + lane] = val;   // 32B contiguous store
    }
}

// ---------------- K2: out[b][t][c] = ctx[b,:]·W[c,:] + bias, bcast over t -------
// grid (Cd/CG=128, Bd/4=16) = 2048 blocks, 256 thr (4 waves).
// wave w owns K-slice h in [w*128, w*128+128); lane = cpart*16 + hp.
__global__ __launch_bounds__(256) void gemm_bcast(const float* __restrict__ ctx,
                                                  const float* __restrict__ Wgen,
                                                  const float* __restrict__ bgen,
                                                  float* __restrict__ out) {
    __shared__ float part[4 * CG * 4];  // [wave][c_local][b_local]
    const int tid   = threadIdx.x;
    const int w     = tid >> 6;
    const int lane  = tid & 63;
    const int cpart = lane >> 4;
    const int hp    = lane & 15;
    const int cblk  = blockIdx.x * CG;
    const int b0    = blockIdx.y * 4;

    const float4* W4 = reinterpret_cast<const float4*>(Wgen);
    const float4* X4 = reinterpret_cast<const float4*>(ctx);

    // ctx registers: xr[bb][j] = ctx[b0+bb][w*128 + j*64 + hp*4 .. +3]
    float4 xr[4][2];
    #pragma unroll
    for (int bb = 0; bb < 4; ++bb)
        #pragma unroll
        for (int j = 0; j < 2; ++j)
            xr[bb][j] = X4[(size_t)(b0 + bb) * 128 + w * 32 + j * 16 + hp];

    #pragma unroll
    for (int q = 0; q < CG / 4; ++q) {       // fully unrolled: 16 W loads in flight
        const int c = cblk + q * 4 + cpart;
        const size_t base = (size_t)c * 128 + w * 32 + hp;
        const float4 w0 = W4[base];
        const float4 w1 = W4[base + 16];
        float acc[4];
        #pragma unroll
        for (int bb = 0; bb < 4; ++bb) {
            float a = w0.x * xr[bb][0].x + w0.y * xr[bb][0].y
                    + w0.z * xr[bb][0].z + w0.w * xr[bb][0].w
                    + w1.x * xr[bb][1].x + w1.y * xr[bb][1].y
                    + w1.z * xr[bb][1].z + w1.w * xr[bb][1].w;
            a = ror_add<0x128>(a);
            a = ror_add<0x124>(a);
            a = ror_add<0x122>(a);
            a = ror_add<0x121>(a);      // full 16-lane sum in every lane
            acc[bb] = a;
        }
        if (hp == 0) {
            reinterpret_cast<float4*>(part)[w * CG + (q * 4 + cpart)] =
                make_float4(acc[0], acc[1], acc[2], acc[3]);
        }
    }
    __syncthreads();

    // combine wave-partials + bias; float4 broadcast stores (1KB/wave/instr).
    {
        const int cq = tid & 7;
        const int bl = (tid >> 3) & 3;
        const int tt = tid >> 5;
        float v[4];
        #pragma unroll
        for (int j = 0; j < 4; ++j) {
            const int cl = cq * 4 + j;
            v[j] = part[(0 * CG + cl) * 4 + bl] + part[(1 * CG + cl) * 4 + bl]
                 + part[(2 * CG + cl) * 4 + bl] + part[(3 * CG + cl) * 4 + bl]
                 + bgen[cblk + cl];
        }
        const float4 vv = make_float4(v[0], v[1], v[2], v[3]);
        float* o = out + (size_t)(b0 + bl) * Td * Cd + cblk + cq * 4;
        #pragma unroll
        for (int k = 0; k < 4; ++k) {
            const int t = tt + k * 8;
            *reinterpret_cast<float4*>(o + (size_t)t * Cd) = vv;
        }
    }
}

extern "C" void kernel_launch(void* const* d_in, const int* in_sizes, int n_in,
                              void* d_out, int out_size, void* d_ws, size_t ws_size,
                              hipStream_t stream) {
    const float* fmap = (const float*)d_in[0];   // [64,512,8,32]
    const float* Wgen = (const float*)d_in[9];   // [4096,512]
    const float* bgen = (const float*)d_in[10];  // [4096]
    float* out = (float*)d_out;                  // [64,32,4096]
    float* ctx = (float*)d_ws;                   // [64,512] scratch

    reduce_rows<<<dim3((Bd * Hd) / (4 * 8)), dim3(256), 0, stream>>>(fmap, ctx);
    gemm_bcast<<<dim3(Cd / CG, Bd / 4), dim3(256), 0, stream>>>(ctx, Wgen, bgen, out);
}